// Round 8
// baseline (78.806 us; speedup 1.0000x reference)
//
#include <hip/hip_runtime.h>
#include <hip/hip_cooperative_groups.h>
#include <hip/hip_bf16.h>
#include <math.h>

namespace cg = cooperative_groups;

#define NB 4096
#define NC 512
#define NF 128
#define NK 256           // GEMM K = 2*F  (k<128: xn^2 . iv ; k>=128: xn . -2*mu*iv)
#define TAUc 32.0f
#define ALPHAc 0.9f

typedef __attribute__((ext_vector_type(8))) short bf16x8;
typedef __attribute__((ext_vector_type(4))) float f32x4;
typedef __attribute__((address_space(1))) const unsigned int gu32;
typedef __attribute__((address_space(3))) unsigned int lu32;

// Truncation-based bf16 hi/lo split: hi = trunc16(x), lo = trunc16(x - hi).
__device__ inline void splitbf(float x, short& hi, short& lo) {
  unsigned u = __float_as_uint(x);
  hi = (short)(u >> 16);
  float l = x - __uint_as_float(u & 0xFFFF0000u);
  lo = (short)(__float_as_uint(l) >> 16);
}

// ---------- fallback-only mask machinery (not launched when Csel==NC) ------------
__global__ __launch_bounds__(512) void k_zero(int* __restrict__ colnz) {
  colnz[threadIdx.x] = 0;
}

__global__ __launch_bounds__(256) void k_mask(const int* __restrict__ T,
                                              int* __restrict__ colnz) {
  int r0 = blockIdx.x * 16;
  int a0 = 0, a1 = 0;
  for (int r = 0; r < 16; ++r) {
    const int* row = T + (size_t)(r0 + r) * NC;
    a0 |= row[threadIdx.x];
    a1 |= row[threadIdx.x + 256];
  }
  if (a0) atomicOr(colnz + threadIdx.x, 1);
  if (a1) atomicOr(colnz + threadIdx.x + 256, 1);
}

__global__ __launch_bounds__(512) void k_scan(const int* __restrict__ colnz,
                                              int* __restrict__ pos) {
  __shared__ int s[NC];
  int t = threadIdx.x;
  int f = colnz[t] ? 1 : 0;
  s[t] = f;
  __syncthreads();
  for (int o = 1; o < NC; o <<= 1) {
    int add = (t >= o) ? s[t - o] : 0;
    __syncthreads();
    s[t] += add;
    __syncthreads();
  }
  pos[t] = s[t] - f;
}

// ---------- mono: prep -> grid.sync -> fused GEMM+softmax+S -> grid.sync -> loss --
// Cooperative, 256 blocks x 512 threads (1 block/CU, exactly co-resident).
// Phase 1: block b preps classes 2b, 2b+1 -> swizzled Bh/Bl + t3.
//          grid.sync release-fence makes the cross-XCD B writes visible.
// Phase 2: identical to round-7 k_fused (wave-private gload_lds B stream,
//          counted vmcnt(8), D-tile in LDS, softmax+S+partials).
// Phase 3: block 0 tree-reduces the 256 partials -> loss.
__global__ __launch_bounds__(512) void k_mono(const float* __restrict__ X,
                                              const int* __restrict__ T,
                                              const float* __restrict__ means,
                                              const float* __restrict__ logv,
                                              ushort* __restrict__ Bh,
                                              ushort* __restrict__ Bl,
                                              float* __restrict__ t3,
                                              const int* __restrict__ colnz,
                                              const int* __restrict__ pos,
                                              float* __restrict__ out,
                                              float* __restrict__ blklog,
                                              int* __restrict__ blkcnt,
                                              int Csel, int ident) {
  __shared__ __align__(16) unsigned char smraw[131072];   // B-stage / D-tile / red
  __shared__ float sl16[16];
  __shared__ int sc16[16];
  __shared__ float ph1[8];
  int tid = threadIdx.x;
  int lane = tid & 63, w = tid >> 6;
  int lr = lane & 15, kq = lane >> 4;

  // ================= phase 1: build B (2 classes per block) =================
  {
    float mu = 0.f, iv = 0.f;
    int c = blockIdx.x * 2 + (tid >> 7);
    int f = tid & 127;
    if (tid < 256) {
      mu = means[(size_t)c * NF + f];
      float lv = fminf(fmaxf(logv[(size_t)c * NF + f], 0.f), 6.f);
      iv = __expf(-lv);
      float s = mu * mu;
      #pragma unroll
      for (int o = 1; o < 64; o <<= 1) s += __shfl_xor(s, o, 64);
      if (lane == 0) ph1[w] = s;     // w in 0..3 for tid<256
    }
    __syncthreads();
    if (tid < 256) {
      int half = tid >> 7;
      float tot = ph1[half * 2] + ph1[half * 2 + 1];
      float mun = mu / fmaxf(sqrtf(tot), 1e-12f);
      int ct = c >> 4, clr = c & 15;
      auto swadr = [&](int k) {
        return (size_t)(ct * 8 + (k >> 5)) * 512 + ((k >> 3) & 3) * 128 + clr * 8 + (k & 7);
      };
      short h, l;
      splitbf(iv, h, l);
      size_t a1 = swadr(f);
      Bh[a1] = (ushort)h; Bl[a1] = (ushort)l;
      splitbf(-2.f * mun * iv, h, l);
      size_t a2 = swadr(f + NF);
      Bh[a2] = (ushort)h; Bl[a2] = (ushort)l;
      float t = mun * mun * iv;
      #pragma unroll
      for (int o = 1; o < 64; o <<= 1) t += __shfl_xor(t, o, 64);
      if (lane == 0) ph1[4 + w] = t;
    }
    __syncthreads();
    if (tid < 256 && (tid & 127) == 0) {
      int half = tid >> 7;
      t3[blockIdx.x * 2 + half] = ph1[4 + half * 2] + ph1[4 + half * 2 + 1];
    }
  }
  cg::this_grid().sync();

  // ================= phase 2: fused GEMM + softmax + S =================
  int r0 = blockIdx.x * 16;

  auto stage = [&](int p) {
    int par = p & 1;
    #pragma unroll
    for (int t = 0; t < 4; ++t) {
      size_t goff = (((size_t)(w * 4 + t) * 8 + p) * 64 + lane) * 8;
      unsigned ldso = (unsigned)(w * 16384 + par * 8192 + t * 2048);
      __builtin_amdgcn_global_load_lds((gu32*)(Bh + goff), (lu32*)(smraw + ldso), 16, 0, 0);
      __builtin_amdgcn_global_load_lds((gu32*)(Bl + goff), (lu32*)(smraw + ldso + 1024), 16, 0, 0);
    }
  };
  stage(0);

  // ---- build A fragments in registers ----
  float xv[4][8];
  float rsum = 0.f;
  const float* xrow = X + (size_t)(r0 + lr) * NF + 8 * kq;
  #pragma unroll
  for (int c = 0; c < 4; ++c) {
    float4 u0 = *(const float4*)(xrow + 32 * c);
    float4 u1 = *(const float4*)(xrow + 32 * c + 4);
    xv[c][0] = u0.x; xv[c][1] = u0.y; xv[c][2] = u0.z; xv[c][3] = u0.w;
    xv[c][4] = u1.x; xv[c][5] = u1.y; xv[c][6] = u1.z; xv[c][7] = u1.w;
    #pragma unroll
    for (int j = 0; j < 8; ++j) rsum = fmaf(xv[c][j], xv[c][j], rsum);
  }
  rsum += __shfl_xor(rsum, 16, 64);
  rsum += __shfl_xor(rsum, 32, 64);
  float rn = 1.0f / fmaxf(sqrtf(rsum), 1e-12f);

  bf16x8 Afh[8], Afl[8];
  #pragma unroll
  for (int c = 0; c < 4; ++c) {
    #pragma unroll
    for (int j = 0; j < 8; ++j) {
      float xn = xv[c][j] * rn;
      short h, l;
      splitbf(xn * xn, h, l);
      Afh[c][j] = h; Afl[c][j] = l;
      splitbf(xn, h, l);
      Afh[c + 4][j] = h; Afl[c + 4][j] = l;
    }
  }

  // ---- prefetch epilogue T rows ----
  int tf0[8], tf1[8];
  {
    const int* Trow0 = T + (size_t)(r0 + 2 * w) * NC;
    const int* Trow1 = T + (size_t)(r0 + 2 * w + 1) * NC;
    #pragma unroll
    for (int j = 0; j < 8; ++j) {
      tf0[j] = Trow0[lane + 64 * j];
      tf1[j] = Trow1[lane + 64 * j];
    }
  }

  // ---- MFMA main loop ----
  const bf16x8* wstage = (const bf16x8*)(smraw + w * 16384);
  f32x4 acc[4] = {};
  #pragma unroll
  for (int k8 = 0; k8 < 8; ++k8) {
    if (k8 < 7) {
      stage(k8 + 1);
      asm volatile("s_waitcnt vmcnt(8)" ::: "memory");
    } else {
      asm volatile("s_waitcnt vmcnt(0)" ::: "memory");
    }
    int par = k8 & 1;
    #pragma unroll
    for (int t = 0; t < 4; ++t) {
      bf16x8 bh = wstage[(par * 8 + t * 2) * 64 + lane];
      bf16x8 bl = wstage[(par * 8 + t * 2 + 1) * 64 + lane];
      acc[t] = __builtin_amdgcn_mfma_f32_16x16x32_bf16(Afh[k8], bh, acc[t], 0, 0, 0);
      acc[t] = __builtin_amdgcn_mfma_f32_16x16x32_bf16(Afl[k8], bh, acc[t], 0, 0, 0);
      acc[t] = __builtin_amdgcn_mfma_f32_16x16x32_bf16(Afh[k8], bl, acc[t], 0, 0, 0);
    }
  }
  __syncthreads();   // all waves done with B-stage; safe to overwrite with D-tile

  // ---- D tile -> LDS (add t3); C/D layout: col=lane&15, row=4*kq+i ----
  float (*Dls)[514] = (float (*)[514])smraw;
  int n0 = w * 64;
  #pragma unroll
  for (int t = 0; t < 4; ++t) {
    int c = n0 + 16 * t + lr;
    float tt = t3[c];
    #pragma unroll
    for (int i = 0; i < 4; ++i) Dls[4 * kq + i][c] = acc[t][i] + tt;
  }
  __syncthreads();

  // ---- per-row softmax + S + loss terms; wave w handles rows 2w, 2w+1 ----
  #pragma unroll
  for (int rr = 0; rr < 2; ++rr) {
    int r = 2 * w + rr;
    const int* tf = rr ? tf1 : tf0;
    float d[8];
    #pragma unroll
    for (int j = 0; j < 8; ++j) d[j] = Dls[r][lane + 64 * j];
    float dmin = d[0];
    #pragma unroll
    for (int j = 1; j < 8; ++j) dmin = fminf(dmin, d[j]);
    #pragma unroll
    for (int o = 1; o < 64; o <<= 1) dmin = fminf(dmin, __shfl_xor(dmin, o, 64));
    float Z = 0.f, Ps = 0.f;
    #pragma unroll
    for (int j = 0; j < 8; ++j) {
      float p = __expf(TAUc * (dmin - d[j]));
      Z += p;
      if (tf[j]) Ps += p;
    }
    #pragma unroll
    for (int o = 1; o < 64; o <<= 1) { Z += __shfl_xor(Z, o, 64); Ps += __shfl_xor(Ps, o, 64); }
    float* srow = out + 1 + (size_t)(r0 + r) * Csel;
    if (ident) {
      #pragma unroll
      for (int j = 0; j < 8; ++j)
        srow[lane + 64 * j] = tf[j] ? 1.0f : __expf(-ALPHAc * d[j]);
    } else {
      #pragma unroll
      for (int j = 0; j < 8; ++j) {
        int c = lane + 64 * j;
        if (colnz[c]) srow[pos[c]] = tf[j] ? 1.0f : __expf(-ALPHAc * d[j]);
      }
    }
    if (lane == 0) {
      float Psum = Ps / Z;
      sl16[r] = (Psum > 0.f) ? logf(Psum) : 0.f;
      sc16[r] = (Psum > 0.f) ? 1 : 0;
    }
  }
  __syncthreads();
  if (tid == 0) {
    float s = 0.f; int c = 0;
    #pragma unroll
    for (int r = 0; r < 16; ++r) { s += sl16[r]; c += sc16[r]; }
    blklog[blockIdx.x] = s;
    blkcnt[blockIdx.x] = c;
    __threadfence();
  }
  cg::this_grid().sync();

  // ================= phase 3: block 0 finalizes the loss =================
  if (blockIdx.x == 0) {
    float* rf = (float*)smraw;
    int*   ri = (int*)(smraw + 2048);
    if (tid < 256) { rf[tid] = blklog[tid]; ri[tid] = blkcnt[tid]; }
    __syncthreads();
    for (int o = 128; o > 0; o >>= 1) {
      if (tid < o) { rf[tid] += rf[tid + o]; ri[tid] += ri[tid + o]; }
      __syncthreads();
    }
    if (tid == 0) out[0] = -rf[0] / fmaxf((float)ri[0], 1.0f);
  }
}

extern "C" void kernel_launch(void* const* d_in, const int* in_sizes, int n_in,
                              void* d_out, int out_size, void* d_ws, size_t ws_size,
                              hipStream_t stream) {
  const float* X     = (const float*)d_in[0];
  const int*   T     = (const int*)d_in[1];
  const float* means = (const float*)d_in[2];
  const float* logv  = (const float*)d_in[3];
  float* out = (float*)d_out;
  char* ws = (char*)d_ws;

  ushort* Bh      = (ushort*)(ws);                  // 256 KB
  ushort* Bl      = (ushort*)(ws + 262144);         // 256 KB
  float*  t3      = (float*) (ws + 524288);         // 2 KB
  float*  blklog  = (float*) (ws + 526336);         // 1 KB
  int*    blkcnt  = (int*)   (ws + 527360);         // 1 KB
  int*    colnz   = (int*)   (ws + 528384);         // 2 KB
  int*    pos     = (int*)   (ws + 530432);         // 2 KB

  int Csel = (out_size - 1) / NB;
  int ident = (Csel == NC);   // Csel==NC forces all-ones mask (pos = identity)

  if (!ident) {
    k_zero<<<1, NC, 0, stream>>>(colnz);
    k_mask<<<NB / 16, 256, 0, stream>>>(T, colnz);
    k_scan<<<1, NC, 0, stream>>>(colnz, pos);
  }

  void* args[] = { (void*)&X, (void*)&T, (void*)&means, (void*)&logv,
                   (void*)&Bh, (void*)&Bl, (void*)&t3,
                   (void*)&colnz, (void*)&pos,
                   (void*)&out, (void*)&blklog, (void*)&blkcnt,
                   (void*)&Csel, (void*)&ident };
  hipLaunchCooperativeKernel((const void*)k_mono, dim3(NB / 16), dim3(512),
                             args, 0, stream);
}

// Round 9
// 23.873 us; speedup vs baseline: 3.3010x; 3.3010x over previous
//
#include <hip/hip_runtime.h>
#include <hip/hip_bf16.h>
#include <math.h>

#define NB 4096
#define NC 512
#define NF 128
#define NK 256           // GEMM K = 2*F  (k<128: xn^2 . iv ; k>=128: xn . -2*mu*iv)
#define TAUc 32.0f
#define ALPHAc 0.9f

typedef __attribute__((ext_vector_type(8))) short bf16x8;
typedef __attribute__((ext_vector_type(4))) float f32x4;
typedef __attribute__((address_space(1))) const unsigned int gu32;
typedef __attribute__((address_space(3))) unsigned int lu32;

// Truncation-based bf16 hi/lo split: hi = trunc16(x), lo = trunc16(x - hi).
__device__ inline void splitbf(float x, short& hi, short& lo) {
  unsigned u = __float_as_uint(x);
  hi = (short)(u >> 16);
  float l = x - __uint_as_float(u & 0xFFFF0000u);
  lo = (short)(__float_as_uint(l) >> 16);
}

// ---------- prepB: mu_n, iv=exp(-clip(lv)); B = [iv, -2*mu_n*iv] hi/lo; t3 -------
// B stored PRE-SWIZZLED in MFMA fragment order: elem = ((ct*8 + k8)*64 + lane)*8 + j
// (col = ct*16 + lr, k = 32*k8 + 8*kq + j, lane = kq*16 + lr). A 128-col group's
// slice (ct in [gc*8, gc*8+8)) is a CONTIGUOUS 64 KB range -> bulk LDS stage.
__global__ __launch_bounds__(128) void k_prepB(const float* __restrict__ means,
                                               const float* __restrict__ logv,
                                               ushort* __restrict__ Bh,
                                               ushort* __restrict__ Bl,
                                               float* __restrict__ t3) {
  __shared__ float p2[2];
  __shared__ float q2[2];
  int c = blockIdx.x, f = threadIdx.x;
  float mu = means[(size_t)c * NF + f];
  float lv = fminf(fmaxf(logv[(size_t)c * NF + f], 0.f), 6.f);
  float iv = __expf(-lv);
  float s = mu * mu;
  #pragma unroll
  for (int o = 1; o < 64; o <<= 1) s += __shfl_xor(s, o, 64);
  if ((f & 63) == 0) p2[f >> 6] = s;
  __syncthreads();
  float mun = mu / fmaxf(sqrtf(p2[0] + p2[1]), 1e-12f);

  int ct = c >> 4, lr = c & 15;
  auto swadr = [&](int k) {
    return (size_t)(ct * 8 + (k >> 5)) * 512 + ((k >> 3) & 3) * 128 + lr * 8 + (k & 7);
  };
  short h, l;
  splitbf(iv, h, l);
  size_t a1 = swadr(f);
  Bh[a1] = (ushort)h; Bl[a1] = (ushort)l;
  splitbf(-2.f * mun * iv, h, l);
  size_t a2 = swadr(f + NF);
  Bh[a2] = (ushort)h; Bl[a2] = (ushort)l;

  float t = mun * mun * iv;
  #pragma unroll
  for (int o = 1; o < 64; o <<= 1) t += __shfl_xor(t, o, 64);
  if ((f & 63) == 0) q2[f >> 6] = t;
  __syncthreads();
  if (f == 0) t3[c] = q2[0] + q2[1];
}

// ---------- fallback-only mask machinery (not launched when Csel==NC) ------------
__global__ __launch_bounds__(512) void k_zero(int* __restrict__ colnz) {
  colnz[threadIdx.x] = 0;
}

__global__ __launch_bounds__(256) void k_mask(const int* __restrict__ T,
                                              int* __restrict__ colnz) {
  int r0 = blockIdx.x * 16;
  int a0 = 0, a1 = 0;
  for (int r = 0; r < 16; ++r) {
    const int* row = T + (size_t)(r0 + r) * NC;
    a0 |= row[threadIdx.x];
    a1 |= row[threadIdx.x + 256];
  }
  if (a0) atomicOr(colnz + threadIdx.x, 1);
  if (a1) atomicOr(colnz + threadIdx.x + 256, 1);
}

__global__ __launch_bounds__(512) void k_scan(const int* __restrict__ colnz,
                                              int* __restrict__ pos) {
  __shared__ int s[NC];
  int t = threadIdx.x;
  int f = colnz[t] ? 1 : 0;
  s[t] = f;
  __syncthreads();
  for (int o = 1; o < NC; o <<= 1) {
    int add = (t >= o) ? s[t - o] : 0;
    __syncthreads();
    s[t] += add;
    __syncthreads();
  }
  pos[t] = s[t] - f;
}

// ---------- fused v9: 64 rows x 128 cols per block; LDS-SHARED B slice -----------
// grid = 64 row-groups x 4 col-groups = 256 blocks, 512 threads = 8 waves.
// Wave (wm = w&3, wn = w>>2) owns rows [wm*16,+16) x cols [wn*64,+64).
// B-slice (128 KB, fragment-ordered, contiguous) staged ONCE into LDS and read
// by all waves -> per-block L2 traffic 128 KB (was 512 KB per-wave-private).
// Rows are wave-private -> softmax runs from accumulators, NO D-tile roundtrip.
// Softmax is PARTIAL per col-group: (m, Z, P) per row published to ws.
__global__ __launch_bounds__(512) void k_fused(const float* __restrict__ X,
                                               const int* __restrict__ T,
                                               const ushort* __restrict__ Bh,
                                               const ushort* __restrict__ Bl,
                                               const float* __restrict__ t3,
                                               const int* __restrict__ colnz,
                                               const int* __restrict__ pos,
                                               float* __restrict__ Sout,
                                               float* __restrict__ rowm,
                                               float* __restrict__ rowz,
                                               float* __restrict__ rowp,
                                               int Csel, int ident) {
  __shared__ __align__(16) unsigned char smB[131072];   // Bh slice @0, Bl @64K
  __shared__ float partm[2][64], partz[2][64], partp[2][64];
  int tid = threadIdx.x;
  int lane = tid & 63, w = tid >> 6;
  int wm = w & 3, wn = w >> 2;
  int lr = lane & 15, kq = lane >> 4;
  int bx = blockIdx.x;
  int gc = bx & 3, gr = bx >> 2;
  int r0 = gr * 64, c0 = gc * 128;

  // ---- stage B slice (128 KB) -> LDS, linear copy (frag order == linear) ----
  {
    const ushort* gh = Bh + (size_t)gc * 32768;
    const ushort* gl = Bl + (size_t)gc * 32768;
    #pragma unroll
    for (int s = 0; s < 8; ++s) {
      unsigned lo = (unsigned)(s * 8192 + w * 1024);   // wave-uniform base
      size_t ge = (size_t)(s * 512 + w * 64 + lane) * 8;
      __builtin_amdgcn_global_load_lds((gu32*)(gh + ge), (lu32*)(smB + lo), 16, 0, 0);
      __builtin_amdgcn_global_load_lds((gu32*)(gl + ge), (lu32*)(smB + 65536 + lo), 16, 0, 0);
    }
  }

  // ---- build A fragments (rows r0 + wm*16 + lr); overlaps the B stage ----
  bf16x8 Afh[8], Afl[8];
  {
    float xv[4][8];
    float rsum = 0.f;
    const float* xrow = X + (size_t)(r0 + wm * 16 + lr) * NF + 8 * kq;
    #pragma unroll
    for (int c = 0; c < 4; ++c) {
      float4 u0 = *(const float4*)(xrow + 32 * c);
      float4 u1 = *(const float4*)(xrow + 32 * c + 4);
      xv[c][0] = u0.x; xv[c][1] = u0.y; xv[c][2] = u0.z; xv[c][3] = u0.w;
      xv[c][4] = u1.x; xv[c][5] = u1.y; xv[c][6] = u1.z; xv[c][7] = u1.w;
      #pragma unroll
      for (int j = 0; j < 8; ++j) rsum = fmaf(xv[c][j], xv[c][j], rsum);
    }
    rsum += __shfl_xor(rsum, 16, 64);
    rsum += __shfl_xor(rsum, 32, 64);
    float rn = 1.0f / fmaxf(sqrtf(rsum), 1e-12f);
    #pragma unroll
    for (int c = 0; c < 4; ++c) {
      #pragma unroll
      for (int j = 0; j < 8; ++j) {
        float xn = xv[c][j] * rn;
        short h, l;
        splitbf(xn * xn, h, l);
        Afh[c][j] = h; Afl[c][j] = l;
        splitbf(xn, h, l);
        Afh[c + 4][j] = h; Afl[c + 4][j] = l;
      }
    }
  }

  // ---- prefetch T patch (16 values/lane; completes under the stage) ----
  int tfv[4][4];
  #pragma unroll
  for (int i = 0; i < 4; ++i) {
    const int* tr = T + (size_t)(r0 + wm * 16 + 4 * kq + i) * NC + c0 + wn * 64 + lr;
    #pragma unroll
    for (int t = 0; t < 4; ++t) tfv[t][i] = tr[16 * t];
  }

  __syncthreads();   // B slice resident (compiler drains vmcnt before barrier)

  // ---- MFMA: 3-product split-bf16; B frags from shared LDS ----
  f32x4 acc[4] = {};
  #pragma unroll
  for (int k8 = 0; k8 < 8; ++k8) {
    #pragma unroll
    for (int t = 0; t < 4; ++t) {
      unsigned off = (unsigned)((((wn * 4 + t) * 8 + k8) * 64 + lane) * 16);
      bf16x8 bh = *(const bf16x8*)(smB + off);
      bf16x8 bl = *(const bf16x8*)(smB + 65536 + off);
      acc[t] = __builtin_amdgcn_mfma_f32_16x16x32_bf16(Afh[k8], bh, acc[t], 0, 0, 0);
      acc[t] = __builtin_amdgcn_mfma_f32_16x16x32_bf16(Afl[k8], bh, acc[t], 0, 0, 0);
      acc[t] = __builtin_amdgcn_mfma_f32_16x16x32_bf16(Afh[k8], bl, acc[t], 0, 0, 0);
    }
  }

  // ---- D in registers: d[t][i] = acc + t3 ; C/D layout col=lr, row=4*kq+i ----
  float d[4][4];
  #pragma unroll
  for (int t = 0; t < 4; ++t) {
    float tt = t3[c0 + wn * 64 + 16 * t + lr];
    #pragma unroll
    for (int i = 0; i < 4; ++i) d[t][i] = acc[t][i] + tt;
  }

  // ---- partial softmax over this wave's 64 cols (reduce over t and lr-group) ----
  float m4[4], Zi[4], Pi[4];
  #pragma unroll
  for (int i = 0; i < 4; ++i) {
    float mm = fminf(fminf(d[0][i], d[1][i]), fminf(d[2][i], d[3][i]));
    #pragma unroll
    for (int o = 1; o < 16; o <<= 1) mm = fminf(mm, __shfl_xor(mm, o, 64));
    float Z = 0.f, P = 0.f;
    #pragma unroll
    for (int t = 0; t < 4; ++t) {
      float p = __expf(TAUc * (mm - d[t][i]));
      Z += p;
      if (tfv[t][i]) P += p;
    }
    #pragma unroll
    for (int o = 1; o < 16; o <<= 1) { Z += __shfl_xor(Z, o, 64); P += __shfl_xor(P, o, 64); }
    m4[i] = mm; Zi[i] = Z; Pi[i] = P;
  }

  // ---- S patch (column-local, no cross-group dependency) ----
  if (ident) {
    #pragma unroll
    for (int i = 0; i < 4; ++i) {
      float* srow = Sout + (size_t)(r0 + wm * 16 + 4 * kq + i) * NC + c0 + wn * 64 + lr;
      #pragma unroll
      for (int t = 0; t < 4; ++t)
        srow[16 * t] = tfv[t][i] ? 1.0f : __expf(-ALPHAc * d[t][i]);
    }
  } else {
    #pragma unroll
    for (int i = 0; i < 4; ++i) {
      float* srow = Sout + (size_t)(r0 + wm * 16 + 4 * kq + i) * Csel;
      #pragma unroll
      for (int t = 0; t < 4; ++t) {
        int c = c0 + wn * 64 + 16 * t + lr;
        if (colnz[c]) srow[pos[c]] = tfv[t][i] ? 1.0f : __expf(-ALPHAc * d[t][i]);
      }
    }
  }

  // ---- combine wn-halves in LDS, publish per-(row, col-group) partials ----
  if (lr == 0) {
    #pragma unroll
    for (int i = 0; i < 4; ++i) {
      int row = wm * 16 + 4 * kq + i;
      partm[wn][row] = m4[i];
      partz[wn][row] = Zi[i];
      partp[wn][row] = Pi[i];
    }
  }
  __syncthreads();
  if (tid < 64) {
    float m0 = partm[0][tid], m1 = partm[1][tid];
    float m = fminf(m0, m1);
    float e0 = __expf(TAUc * (m - m0)), e1 = __expf(TAUc * (m - m1));
    int g = (r0 + tid) * 4 + gc;
    rowm[g] = m;
    rowz[g] = partz[0][tid] * e0 + partz[1][tid] * e1;
    rowp[g] = partp[0][tid] * e0 + partp[1][tid] * e1;
  }
}

// ---------- fin2: combine 4 col-group partials per row -> loss -------------------
__global__ __launch_bounds__(1024) void k_fin(const float* __restrict__ rowm,
                                              const float* __restrict__ rowz,
                                              const float* __restrict__ rowp,
                                              float* __restrict__ out) {
  __shared__ float sl[16];
  __shared__ int sc[16];
  int tid = threadIdx.x;
  int lane = tid & 63, w = tid >> 6;
  float ls = 0.f; int lc = 0;
  for (int r = tid; r < NB; r += 1024) {
    float4 mv = ((const float4*)rowm)[r];
    float4 zv = ((const float4*)rowz)[r];
    float4 pv = ((const float4*)rowp)[r];
    float m = fminf(fminf(mv.x, mv.y), fminf(mv.z, mv.w));
    float e0 = __expf(TAUc * (m - mv.x));
    float e1 = __expf(TAUc * (m - mv.y));
    float e2 = __expf(TAUc * (m - mv.z));
    float e3 = __expf(TAUc * (m - mv.w));
    float Z = zv.x * e0 + zv.y * e1 + zv.z * e2 + zv.w * e3;
    float P = pv.x * e0 + pv.y * e1 + pv.z * e2 + pv.w * e3;
    float Ps = P / Z;
    if (Ps > 0.f) { ls += logf(Ps); ++lc; }
  }
  #pragma unroll
  for (int o = 1; o < 64; o <<= 1) { ls += __shfl_xor(ls, o, 64); lc += __shfl_xor(lc, o, 64); }
  if (lane == 0) { sl[w] = ls; sc[w] = lc; }
  __syncthreads();
  if (tid == 0) {
    float s = 0.f; int c = 0;
    #pragma unroll
    for (int i = 0; i < 16; ++i) { s += sl[i]; c += sc[i]; }
    out[0] = -s / fmaxf((float)c, 1.0f);
  }
}

extern "C" void kernel_launch(void* const* d_in, const int* in_sizes, int n_in,
                              void* d_out, int out_size, void* d_ws, size_t ws_size,
                              hipStream_t stream) {
  const float* X     = (const float*)d_in[0];
  const int*   T     = (const int*)d_in[1];
  const float* means = (const float*)d_in[2];
  const float* logv  = (const float*)d_in[3];
  float* out = (float*)d_out;
  char* ws = (char*)d_ws;

  ushort* Bh   = (ushort*)(ws);                  // 256 KB
  ushort* Bl   = (ushort*)(ws + 262144);         // 256 KB
  float*  t3   = (float*) (ws + 524288);         // 2 KB
  float*  rowm = (float*) (ws + 526336);         // 64 KB  [4096][4]
  float*  rowz = (float*) (ws + 591872);         // 64 KB
  float*  rowp = (float*) (ws + 657408);         // 64 KB
  int*    colnz= (int*)   (ws + 722944);         // 2 KB
  int*    pos  = (int*)   (ws + 724992);         // 2 KB

  int Csel = (out_size - 1) / NB;
  int ident = (Csel == NC);   // Csel==NC forces all-ones mask (pos = identity)

  k_prepB<<<NC, NF, 0, stream>>>(means, logv, Bh, Bl, t3);
  if (!ident) {
    k_zero<<<1, NC, 0, stream>>>(colnz);
    k_mask<<<NB / 16, 256, 0, stream>>>(T, colnz);
    k_scan<<<1, NC, 0, stream>>>(colnz, pos);
  }
  k_fused<<<256, 512, 0, stream>>>(X, T, Bh, Bl, t3, colnz, pos,
                                   out + 1, rowm, rowz, rowp, Csel, ident);
  k_fin<<<1, 1024, 0, stream>>>(rowm, rowz, rowp, out);
}

// Round 10
// 22.043 us; speedup vs baseline: 3.5752x; 1.0831x over previous
//
#include <hip/hip_runtime.h>
#include <hip/hip_bf16.h>
#include <math.h>

#define NB 4096
#define NC 512
#define NF 128
#define NK 256           // GEMM K = 2*F  (k<128: xn^2 . iv ; k>=128: xn . -2*mu*iv)
#define TAUc 32.0f
#define ALPHAc 0.9f

typedef __attribute__((ext_vector_type(8))) short bf16x8;
typedef __attribute__((ext_vector_type(4))) float f32x4;

// Truncation-based bf16 hi/lo split: hi = trunc16(x), lo = trunc16(x - hi).
__device__ inline void splitbf(float x, short& hi, short& lo) {
  unsigned u = __float_as_uint(x);
  hi = (short)(u >> 16);
  float l = x - __uint_as_float(u & 0xFFFF0000u);
  lo = (short)(__float_as_uint(l) >> 16);
}

// ---------- fallback-only mask machinery (not launched when Csel==NC) ------------
__global__ __launch_bounds__(512) void k_zero(int* __restrict__ colnz) {
  colnz[threadIdx.x] = 0;
}

__global__ __launch_bounds__(256) void k_mask(const int* __restrict__ T,
                                              int* __restrict__ colnz) {
  int r0 = blockIdx.x * 16;
  int a0 = 0, a1 = 0;
  for (int r = 0; r < 16; ++r) {
    const int* row = T + (size_t)(r0 + r) * NC;
    a0 |= row[threadIdx.x];
    a1 |= row[threadIdx.x + 256];
  }
  if (a0) atomicOr(colnz + threadIdx.x, 1);
  if (a1) atomicOr(colnz + threadIdx.x + 256, 1);
}

__global__ __launch_bounds__(512) void k_scan(const int* __restrict__ colnz,
                                              int* __restrict__ pos) {
  __shared__ int s[NC];
  int t = threadIdx.x;
  int f = colnz[t] ? 1 : 0;
  s[t] = f;
  __syncthreads();
  for (int o = 1; o < NC; o <<= 1) {
    int add = (t >= o) ? s[t - o] : 0;
    __syncthreads();
    s[t] += add;
    __syncthreads();
  }
  pos[t] = s[t] - f;
}

// ---------- fused v10: in-block B build + GEMM + partial softmax + S -------------
// grid = 64 row-groups x 4 col-groups = 256 blocks, 512 threads = 8 waves.
// Phase A (no global B at all): thread (class = tid>>2, quarter q = tid&3)
//   computes its class's mu_n/iv/t3, trunc-splits, and ds_write_b128's the
//   fragments STRAIGHT INTO LDS in MFMA fragment order (same layout R6-R9
//   verified). Class norm via 4-lane shfl reduction. t3 kept in LDS.
// Phase B: identical to round-9 (A in registers, 3-product split-bf16 MFMA,
//   rows wave-private -> softmax from accumulators, partial (m,Z,P) publish).
__global__ __launch_bounds__(512) void k_fused(const float* __restrict__ X,
                                               const int* __restrict__ T,
                                               const float* __restrict__ means,
                                               const float* __restrict__ logv,
                                               const int* __restrict__ colnz,
                                               const int* __restrict__ pos,
                                               float* __restrict__ Sout,
                                               float* __restrict__ rowm,
                                               float* __restrict__ rowz,
                                               float* __restrict__ rowp,
                                               int Csel, int ident) {
  __shared__ __align__(16) unsigned char smB[131072];   // Bh slice @0, Bl @64K
  __shared__ float t3s[128];
  __shared__ float partm[2][64], partz[2][64], partp[2][64];
  int tid = threadIdx.x;
  int lane = tid & 63, w = tid >> 6;
  int wm = w & 3, wn = w >> 2;
  int lr = lane & 15, kq = lane >> 4;
  int bx = blockIdx.x;
  int gc = bx & 3, gr = bx >> 2;
  int r0 = gr * 64, c0 = gc * 128;

  // ---- B-build: this thread owns class cls, f in [32q, 32q+32) ----
  int cls = w * 16 + (lane >> 2);        // block-local class 0..127
  int q = lane & 3;
  int c15 = (lane >> 2) & 15;
  float mua[32], lva[32];
  {
    const float4* mp = (const float4*)(means + (size_t)(c0 + cls) * NF + 32 * q);
    const float4* lp = (const float4*)(logv + (size_t)(c0 + cls) * NF + 32 * q);
    #pragma unroll
    for (int i = 0; i < 8; ++i) {
      *(float4*)(mua + 4 * i) = mp[i];
      *(float4*)(lva + 4 * i) = lp[i];
    }
  }

  // ---- A-input loads issue here (independent; overlap B compute) ----
  float xv[4][8];
  {
    const float* xrow = X + (size_t)(r0 + wm * 16 + lr) * NF + 8 * kq;
    #pragma unroll
    for (int c = 0; c < 4; ++c) {
      float4 u0 = *(const float4*)(xrow + 32 * c);
      float4 u1 = *(const float4*)(xrow + 32 * c + 4);
      xv[c][0] = u0.x; xv[c][1] = u0.y; xv[c][2] = u0.z; xv[c][3] = u0.w;
      xv[c][4] = u1.x; xv[c][5] = u1.y; xv[c][6] = u1.z; xv[c][7] = u1.w;
    }
  }
  // ---- T patch prefetch ----
  int tfv[4][4];
  #pragma unroll
  for (int i = 0; i < 4; ++i) {
    const int* tr = T + (size_t)(r0 + wm * 16 + 4 * kq + i) * NC + c0 + wn * 64 + lr;
    #pragma unroll
    for (int t = 0; t < 4; ++t) tfv[t][i] = tr[16 * t];
  }

  // ---- B compute: class norm (4-lane reduce), split, fragment-order LDS write --
  {
    float s = 0.f;
    #pragma unroll
    for (int k = 0; k < 32; ++k) s = fmaf(mua[k], mua[k], s);
    s += __shfl_xor(s, 1, 64);
    s += __shfl_xor(s, 2, 64);
    float rn_c = 1.0f / fmaxf(sqrtf(s), 1e-12f);
    float t3a = 0.f;
    #pragma unroll
    for (int i8 = 0; i8 < 4; ++i8) {
      bf16x8 h1, l1, h2, l2;
      #pragma unroll
      for (int j = 0; j < 8; ++j) {
        int jj = i8 * 8 + j;
        float ivv = __expf(-fminf(fmaxf(lva[jj], 0.f), 6.f));
        float m = mua[jj] * rn_c;
        short h, l;
        splitbf(ivv, h, l);
        h1[j] = h; l1[j] = l;
        splitbf(-2.f * m * ivv, h, l);
        h2[j] = h; l2[j] = l;
        t3a = fmaf(m * m, ivv, t3a);
      }
      // b1 at k5=q, b2 at k5=4+q; elem addr = (w*8+k5)*512 + i8*128 + c15*8
      unsigned e1 = (unsigned)((w * 8 + q) * 512 + i8 * 128 + c15 * 8) * 2u;
      unsigned e2 = (unsigned)((w * 8 + 4 + q) * 512 + i8 * 128 + c15 * 8) * 2u;
      *(bf16x8*)(smB + e1) = h1;
      *(bf16x8*)(smB + 65536 + e1) = l1;
      *(bf16x8*)(smB + e2) = h2;
      *(bf16x8*)(smB + 65536 + e2) = l2;
    }
    t3a += __shfl_xor(t3a, 1, 64);
    t3a += __shfl_xor(t3a, 2, 64);
    if (q == 0) t3s[cls] = t3a;
  }

  // ---- A-build (X already in regs) ----
  bf16x8 Afh[8], Afl[8];
  {
    float rsum = 0.f;
    #pragma unroll
    for (int c = 0; c < 4; ++c)
      #pragma unroll
      for (int j = 0; j < 8; ++j) rsum = fmaf(xv[c][j], xv[c][j], rsum);
    rsum += __shfl_xor(rsum, 16, 64);
    rsum += __shfl_xor(rsum, 32, 64);
    float rn = 1.0f / fmaxf(sqrtf(rsum), 1e-12f);
    #pragma unroll
    for (int c = 0; c < 4; ++c) {
      #pragma unroll
      for (int j = 0; j < 8; ++j) {
        float xn = xv[c][j] * rn;
        short h, l;
        splitbf(xn * xn, h, l);
        Afh[c][j] = h; Afl[c][j] = l;
        splitbf(xn, h, l);
        Afh[c + 4][j] = h; Afl[c + 4][j] = l;
      }
    }
  }

  __syncthreads();   // B slice + t3 resident in LDS

  // ---- MFMA: 3-product split-bf16; B frags from shared LDS ----
  f32x4 acc[4] = {};
  #pragma unroll
  for (int k8 = 0; k8 < 8; ++k8) {
    #pragma unroll
    for (int t = 0; t < 4; ++t) {
      unsigned off = (unsigned)((((wn * 4 + t) * 8 + k8) * 64 + lane) * 16);
      bf16x8 bh = *(const bf16x8*)(smB + off);
      bf16x8 bl = *(const bf16x8*)(smB + 65536 + off);
      acc[t] = __builtin_amdgcn_mfma_f32_16x16x32_bf16(Afh[k8], bh, acc[t], 0, 0, 0);
      acc[t] = __builtin_amdgcn_mfma_f32_16x16x32_bf16(Afl[k8], bh, acc[t], 0, 0, 0);
      acc[t] = __builtin_amdgcn_mfma_f32_16x16x32_bf16(Afh[k8], bl, acc[t], 0, 0, 0);
    }
  }

  // ---- D in registers: d[t][i] = acc + t3 ; C/D layout col=lr, row=4*kq+i ----
  float d[4][4];
  #pragma unroll
  for (int t = 0; t < 4; ++t) {
    float tt = t3s[wn * 64 + 16 * t + lr];
    #pragma unroll
    for (int i = 0; i < 4; ++i) d[t][i] = acc[t][i] + tt;
  }

  // ---- partial softmax over this wave's 64 cols ----
  float m4[4], Zi[4], Pi[4];
  #pragma unroll
  for (int i = 0; i < 4; ++i) {
    float mm = fminf(fminf(d[0][i], d[1][i]), fminf(d[2][i], d[3][i]));
    #pragma unroll
    for (int o = 1; o < 16; o <<= 1) mm = fminf(mm, __shfl_xor(mm, o, 64));
    float Z = 0.f, P = 0.f;
    #pragma unroll
    for (int t = 0; t < 4; ++t) {
      float p = __expf(TAUc * (mm - d[t][i]));
      Z += p;
      if (tfv[t][i]) P += p;
    }
    #pragma unroll
    for (int o = 1; o < 16; o <<= 1) { Z += __shfl_xor(Z, o, 64); P += __shfl_xor(P, o, 64); }
    m4[i] = mm; Zi[i] = Z; Pi[i] = P;
  }

  // ---- S patch (column-local) ----
  if (ident) {
    #pragma unroll
    for (int i = 0; i < 4; ++i) {
      float* srow = Sout + (size_t)(r0 + wm * 16 + 4 * kq + i) * NC + c0 + wn * 64 + lr;
      #pragma unroll
      for (int t = 0; t < 4; ++t)
        srow[16 * t] = tfv[t][i] ? 1.0f : __expf(-ALPHAc * d[t][i]);
    }
  } else {
    #pragma unroll
    for (int i = 0; i < 4; ++i) {
      float* srow = Sout + (size_t)(r0 + wm * 16 + 4 * kq + i) * Csel;
      #pragma unroll
      for (int t = 0; t < 4; ++t) {
        int c = c0 + wn * 64 + 16 * t + lr;
        if (colnz[c]) srow[pos[c]] = tfv[t][i] ? 1.0f : __expf(-ALPHAc * d[t][i]);
      }
    }
  }

  // ---- combine wn-halves in LDS, publish per-(row, col-group) partials ----
  if (lr == 0) {
    #pragma unroll
    for (int i = 0; i < 4; ++i) {
      int row = wm * 16 + 4 * kq + i;
      partm[wn][row] = m4[i];
      partz[wn][row] = Zi[i];
      partp[wn][row] = Pi[i];
    }
  }
  __syncthreads();
  if (tid < 64) {
    float m0 = partm[0][tid], m1 = partm[1][tid];
    float m = fminf(m0, m1);
    float e0 = __expf(TAUc * (m - m0)), e1 = __expf(TAUc * (m - m1));
    int g = (r0 + tid) * 4 + gc;
    rowm[g] = m;
    rowz[g] = partz[0][tid] * e0 + partz[1][tid] * e1;
    rowp[g] = partp[0][tid] * e0 + partp[1][tid] * e1;
  }
}

// ---------- fin: combine 4 col-group partials per row -> loss --------------------
__global__ __launch_bounds__(1024) void k_fin(const float* __restrict__ rowm,
                                              const float* __restrict__ rowz,
                                              const float* __restrict__ rowp,
                                              float* __restrict__ out) {
  __shared__ float sl[16];
  __shared__ int sc[16];
  int tid = threadIdx.x;
  int lane = tid & 63, w = tid >> 6;
  float ls = 0.f; int lc = 0;
  for (int r = tid; r < NB; r += 1024) {
    float4 mv = ((const float4*)rowm)[r];
    float4 zv = ((const float4*)rowz)[r];
    float4 pv = ((const float4*)rowp)[r];
    float m = fminf(fminf(mv.x, mv.y), fminf(mv.z, mv.w));
    float e0 = __expf(TAUc * (m - mv.x));
    float e1 = __expf(TAUc * (m - mv.y));
    float e2 = __expf(TAUc * (m - mv.z));
    float e3 = __expf(TAUc * (m - mv.w));
    float Z = zv.x * e0 + zv.y * e1 + zv.z * e2 + zv.w * e3;
    float P = pv.x * e0 + pv.y * e1 + pv.z * e2 + pv.w * e3;
    float Ps = P / Z;
    if (Ps > 0.f) { ls += logf(Ps); ++lc; }
  }
  #pragma unroll
  for (int o = 1; o < 64; o <<= 1) { ls += __shfl_xor(ls, o, 64); lc += __shfl_xor(lc, o, 64); }
  if (lane == 0) { sl[w] = ls; sc[w] = lc; }
  __syncthreads();
  if (tid == 0) {
    float s = 0.f; int c = 0;
    #pragma unroll
    for (int i = 0; i < 16; ++i) { s += sl[i]; c += sc[i]; }
    out[0] = -s / fmaxf((float)c, 1.0f);
  }
}

extern "C" void kernel_launch(void* const* d_in, const int* in_sizes, int n_in,
                              void* d_out, int out_size, void* d_ws, size_t ws_size,
                              hipStream_t stream) {
  const float* X     = (const float*)d_in[0];
  const int*   T     = (const int*)d_in[1];
  const float* means = (const float*)d_in[2];
  const float* logv  = (const float*)d_in[3];
  float* out = (float*)d_out;
  char* ws = (char*)d_ws;

  float*  rowm = (float*) (ws);                  // 64 KB  [4096][4]
  float*  rowz = (float*) (ws + 65536);          // 64 KB
  float*  rowp = (float*) (ws + 131072);         // 64 KB
  int*    colnz= (int*)   (ws + 196608);         // 2 KB
  int*    pos  = (int*)   (ws + 198656);         // 2 KB

  int Csel = (out_size - 1) / NB;
  int ident = (Csel == NC);   // Csel==NC forces all-ones mask (pos = identity)

  if (!ident) {
    k_zero<<<1, NC, 0, stream>>>(colnz);
    k_mask<<<NB / 16, 256, 0, stream>>>(T, colnz);
    k_scan<<<1, NC, 0, stream>>>(colnz, pos);
  }
  k_fused<<<256, 512, 0, stream>>>(X, T, means, logv, colnz, pos,
                                   out + 1, rowm, rowz, rowp, Csel, ident);
  k_fin<<<1, 1024, 0, stream>>>(rowm, rowz, rowp, out);
}